// Round 2
// baseline (296.665 us; speedup 1.0000x reference)
//
#include <hip/hip_runtime.h>
#include <hip/hip_bf16.h>

typedef __bf16 bf16;
typedef __bf16 bf16x4 __attribute__((ext_vector_type(4)));
typedef __bf16 bf16x8 __attribute__((ext_vector_type(8)));
typedef float f32x4 __attribute__((ext_vector_type(4)));

#define MFMA(a, b, c) __builtin_amdgcn_mfma_f32_16x16x32_bf16(a, b, c, 0, 0, 0)

__device__ inline f32x4 zf4() { return f32x4{0.f, 0.f, 0.f, 0.f}; }

constexpr int Tc = 16, Hc = 56, Wc = 56, Cc = 128, NHc = 4, HDc = 32;
constexpr int VOL = 392;                 // 8*7*7 tokens per window
constexpr int STc = 4, SHc = 3, SWc = 3; // shift
constexpr int TWIN = 256;                // total windows (B * 128)
constexpr int MTOT = TWIN * VOL;         // 100352 tokens
constexpr int QSZ = TWIN * NHc * VOL * HDc;
constexpr int BMT_N = 8 * 4 * 400 * 416; // [pat][head][row][col] bias+mask table

__device__ inline bf16x8 zero8() {
    bf16x8 z;
#pragma unroll
    for (int j = 0; j < 8; ++j) z[j] = (bf16)0.0f;
    return z;
}

__device__ inline f32x4 up4(bf16x4 b) {
    f32x4 r;
#pragma unroll
    for (int j = 0; j < 4; ++j) r[j] = (float)b[j];
    return r;
}

__device__ inline int cls_of(int v, int pt, int ph, int pw) {
    int tt = v / 49, rem = v % 49, hh = rem / 7, ww = rem % 7;
    int ct = pt ? (tt < 4 ? 1 : 2) : 0;
    int ch = ph ? (hh < 4 ? 1 : 2) : 0;
    int cw = pw ? (ww < 4 ? 1 : 2) : 0;
    return ct * 9 + ch * 3 + cw;
}

// ---------------------------------------------------------------------------
// Kernel 0: fused prep. Blocks 0..64: fp32->bf16 param cvt.
// Blocks 65..864: bias+mask table bmt[pat8][head4][row400][col416] bf16 =
//   (rpb + mask)*log2e; pad col -> -144 (exp2 ~ 0), pad row -> 0.
// ---------------------------------------------------------------------------
__global__ void prep_kernel(const float* __restrict__ wq, const float* __restrict__ bq,
                            const float* __restrict__ wp, const float* __restrict__ bp,
                            const float* __restrict__ rpb,
                            bf16* __restrict__ wqb, bf16* __restrict__ bqb,
                            bf16* __restrict__ wpb, bf16* __restrict__ bpb,
                            bf16* __restrict__ bmt) {
    const int blk = blockIdx.x, tid = threadIdx.x;
    if (blk < 65) {
        int i = blk * 256 + tid;
        const float* s; bf16* d; int off;
        if (i < 12288)       { s = wq; d = wqb; off = i; }
        else if (i < 12384)  { s = bq; d = bqb; off = i - 12288; }
        else if (i < 16480)  { s = wp; d = wpb; off = i - 12384; }
        else if (i < 16512)  { s = bp; d = bpb; off = i - 16480; }
        else return;
        f32x4 v = *(const f32x4*)(s + (size_t)off * 4);
        bf16x4 o;
#pragma unroll
        for (int j = 0; j < 4; ++j) o[j] = (bf16)v[j];
        *(bf16x4*)(d + (size_t)off * 4) = o;
        return;
    }
    // bias blocks: bb = (pat, head, rowchunk of 16)
    __shared__ unsigned char clsc[392];
    int bb = blk - 65;
    int pat = bb / 100, rem = bb % 100;
    int head = rem / 25, rc = rem % 25;
    int pt = (pat >> 2) & 1, ph = (pat >> 1) & 1, pw = pat & 1;
    for (int v = tid; v < 392; v += 256) clsc[v] = (unsigned char)cls_of(v, pt, ph, pw);
    __syncthreads();
    bf16* dst = bmt + ((size_t)(pat * NHc + head) * 400 + rc * 16) * 416;
    for (int idx = tid; idx < 16 * 104; idx += 256) {
        int lr = idx / 104, c4 = idx % 104;
        int row = rc * 16 + lr;
        bf16x4 o;
        if (row >= VOL) {
#pragma unroll
            for (int j = 0; j < 4; ++j) o[j] = (bf16)0.f;
        } else {
            int rcls = clsc[row];
            const float* brow = rpb + (size_t)(head * VOL + row) * VOL;
#pragma unroll
            for (int j = 0; j < 4; ++j) {
                int col = c4 * 4 + j;
                float v;
                if (col >= VOL) v = -144.0f;
                else {
                    v = brow[col] * 1.4426950408889634f;
                    if (clsc[col] != rcls) v -= 144.0f;
                }
                o[j] = (bf16)v;
            }
        }
        *(bf16x4*)(dst + (size_t)lr * 416 + c4 * 4) = o;
    }
}

// ---------------------------------------------------------------------------
// Kernel 1: QKV projection (roll+partition fused gather, C^T-layout MFMA).
// Epilogue: 3 phases (q,k,v) reuse As as [64][134] C-staging -> LDS stays
// ~18 KB (4+ blocks/CU) AND stores are full-64B coalesced bf16x8 (no partial-
// sector write amplification). q pre-scaled by log2(e)/sqrt(32).
// ---------------------------------------------------------------------------
__global__ __launch_bounds__(256, 4)
void qkv_kernel(const float* __restrict__ x, const bf16* __restrict__ wq,
                const bf16* __restrict__ bq, bf16* __restrict__ qws,
                bf16* __restrict__ kws, bf16* __restrict__ vws) {
    __shared__ bf16 As[64][136];
    __shared__ unsigned int rb[64];
    __shared__ unsigned int rbw[64];
    const int tid = threadIdx.x;
    const int m0 = blockIdx.x * 64;

    if (tid < 64) {
        int g = m0 + tid;
        int win = g / VOL, tok = g % VOL;
        int b = win >> 7, wi = win & 127;
        int wt_i = wi >> 6, wh_i = (wi >> 3) & 7, ww_i = wi & 7;
        int tt = tok / 49, r2 = tok % 49, hh = r2 / 7, ww2 = r2 % 7;
        int t = wt_i * 8 + tt + STc; if (t >= Tc) t -= Tc;
        int h = wh_i * 7 + hh + SHc; if (h >= Hc) h -= Hc;
        int w = ww_i * 7 + ww2 + SWc; if (w >= Wc) w -= Wc;
        rb[tid] = (unsigned int)((((b * Tc + t) * Hc + h) * Wc + w) * Cc * 4);
        rbw[tid] = (unsigned int)((win << 9) | tok);
    }
    __syncthreads();

    for (int idx = tid; idx < 64 * 32; idx += 256) {
        int r = idx >> 5, c = idx & 31;
        const float* src = (const float*)((const char*)x + rb[r]) + c * 4;
        f32x4 v = *(const f32x4*)src;
        bf16x4 o;
#pragma unroll
        for (int j = 0; j < 4; ++j) o[j] = (bf16)v[j];
        *(bf16x4*)(&As[r][c * 4]) = o;
    }
    __syncthreads();

    const int wid = tid >> 6, lane = tid & 63;
    const int quad = lane >> 4, l15 = lane & 15;
    const int nbase = wid * 96;

    f32x4 acc[6][4];  // [mt = W-col tile][nt = row tile]
#pragma unroll
    for (int mt = 0; mt < 6; ++mt)
#pragma unroll
        for (int nt = 0; nt < 4; ++nt) acc[mt][nt] = zf4();

#pragma unroll
    for (int ko = 0; ko < 4; ++ko) {
        bf16x8 xf[4];  // B-operand: x rows
#pragma unroll
        for (int nt = 0; nt < 4; ++nt)
            xf[nt] = *(const bf16x8*)(&As[nt * 16 + l15][ko * 32 + quad * 8]);
#pragma unroll
        for (int mt = 0; mt < 6; ++mt) {
            bf16x8 wf = *(const bf16x8*)(wq + (size_t)(nbase + mt * 16 + l15) * Cc + ko * 32 + quad * 8);
#pragma unroll
            for (int nt = 0; nt < 4; ++nt)
                acc[mt][nt] = MFMA(wf, xf[nt], acc[mt][nt]);  // C^T: m=col, n=row
        }
    }

    // Epilogue: per output o in {q,k,v}: stage 64x128 cols in (reused) As,
    // then full-64B coalesced stores. As is dead after the MFMA loop.
    bf16 (*Cs)[134] = (bf16(*)[134])&As[0][0];  // stride 134 (67 words, odd): conflict-free writes
#pragma unroll 1
    for (int o = 0; o < 3; ++o) {
        __syncthreads();  // previous phase's As/Cs reads complete
#pragma unroll
        for (int mt = 0; mt < 6; ++mt) {
            int colbase = nbase + mt * 16 + quad * 4;
            if ((colbase >> 7) != o) continue;  // wave-uniform (quad*4 < 16)
            bf16x4 bc = *(const bf16x4*)(bq + colbase);
            float scale = (o == 0) ? 0.25505653942f : 1.0f;  // log2e/sqrt(32) on q
            int lc = colbase & 127;
#pragma unroll
            for (int nt = 0; nt < 4; ++nt) {
                bf16x4 ov;
#pragma unroll
                for (int r = 0; r < 4; ++r)
                    ov[r] = (bf16)((acc[mt][nt][r] + (float)bc[r]) * scale);
                *(bf16x4*)(&Cs[nt * 16 + l15][lc]) = ov;
            }
        }
        __syncthreads();
        bf16* basep = (o == 0) ? qws : (o == 1) ? kws : vws;
        for (int idx = tid; idx < 64 * 16; idx += 256) {
            int r = idx >> 4, c = idx & 15;
            unsigned int p = rbw[r];
            int win = p >> 9, tok = p & 511;
            int hh = c >> 2, hd = (c & 3) * 8;
            *(bf16x8*)(basep + ((size_t)(win * NHc + hh) * VOL + tok) * HDc + hd) =
                *(const bf16x8*)(&Cs[r][c * 8]);
        }
    }
}

// ---------------------------------------------------------------------------
// Kernel 2: windowed attention, S^T formulation, pattern bias table, PV
// pipelined one kt behind QK. 512 thr/WG, one WG per (win,head), 2 q-tiles/wave.
// ---------------------------------------------------------------------------
__global__ __launch_bounds__(512, 4)
void attn_kernel(const bf16* __restrict__ qws, const bf16* __restrict__ kws,
                 const bf16* __restrict__ vws, const bf16* __restrict__ bmt,
                 bf16* __restrict__ aows) {
    __shared__ bf16 Kl[400][40];      // rows 392..399 zero (kt12 is half-tile)
    __shared__ bf16 Vt[32][424];      // V transposed
    __shared__ bf16 Pb[8][2][16][40]; // per-wave, per-tile P

    const int tid = threadIdx.x;
    const int win = blockIdx.x >> 2, head = blockIdx.x & 3;
    const int wi = win & 127;
    const int wt_i = wi >> 6, wh_i = (wi >> 3) & 7, ww_i = wi & 7;
    const int pat = ((wt_i == 1) << 2) | ((wh_i == 7) << 1) | (ww_i == 7);

    const bf16* Qg = qws + (size_t)(win * NHc + head) * VOL * HDc;
    const bf16* Kg = kws + (size_t)(win * NHc + head) * VOL * HDc;
    const bf16* Vg = vws + (size_t)(win * NHc + head) * VOL * HDc;
    const bf16* Bg = bmt + (size_t)(pat * NHc + head) * 400 * 416;

    for (int idx = tid; idx < 400 * 4; idx += 512) {
        int tok = idx >> 2, c = idx & 3;
        bf16x8 v = zero8();
        if (tok < VOL) v = *(const bf16x8*)(Kg + tok * HDc + c * 8);
        *(bf16x8*)(&Kl[tok][c * 8]) = v;
    }
    if (tid < 416) {  // V transpose: b64 chunks of 4 toks
        int c = tid & 3, tok4 = (tid >> 2) * 4;
        bf16x8 rr[4];
#pragma unroll
        for (int i = 0; i < 4; ++i)
            rr[i] = (tok4 + i < VOL) ? *(const bf16x8*)(Vg + (tok4 + i) * HDc + c * 8) : zero8();
#pragma unroll
        for (int j = 0; j < 8; ++j) {
            bf16x4 wv;
            wv[0] = rr[0][j]; wv[1] = rr[1][j]; wv[2] = rr[2][j]; wv[3] = rr[3][j];
            *(bf16x4*)(&Vt[c * 8 + j][tok4]) = wv;
        }
    }
    __syncthreads();

    const int wid = tid >> 6, lane = tid & 63;
    const int quad = lane >> 4, l15 = lane & 15;
    bf16* PwA = &Pb[wid][0][0][0];
    bf16* PwB = &Pb[wid][1][0][0];

    for (int pass = 0; pass < 2; ++pass) {
        const int qtA = pass * 16 + wid, qtB = qtA + 8;
        const bool hasB = (qtB < 25);
        const int qbA = qtA * 16, qbB = qtB * 16;
        int qrA = qbA + l15; if (qrA >= VOL) qrA = VOL - 1;
        const bf16x8 qfA = *(const bf16x8*)(Qg + (size_t)qrA * HDc + quad * 8);
        const bf16* BrA = Bg + (size_t)(qbA + l15) * 416;
        const bf16* BrB = BrA;
        bf16x8 qfB;
        if (hasB) {
            int qrB = qbB + l15; if (qrB >= VOL) qrB = VOL - 1;
            qfB = *(const bf16x8*)(Qg + (size_t)qrB * HDc + quad * 8);
            BrB = Bg + (size_t)(qbB + l15) * 416;
        }
        f32x4 oA0 = zf4(), oA1 = zf4(), oB0 = zf4(), oB1 = zf4();
        float lsA = 0.f, lsB = 0.f;
        bf16x4 nbA0 = *(const bf16x4*)(BrA + quad * 4);
        bf16x4 nbA1 = *(const bf16x4*)(BrA + 16 + quad * 4);
        bf16x4 nbB0, nbB1;
        if (hasB) {
            nbB0 = *(const bf16x4*)(BrB + quad * 4);
            nbB1 = *(const bf16x4*)(BrB + 16 + quad * 4);
        }

        auto qk_full = [&](int kb) {
            bf16x8 kf0 = *(const bf16x8*)(&Kl[kb + l15][quad * 8]);
            bf16x8 kf1 = *(const bf16x8*)(&Kl[kb + 16 + l15][quad * 8]);
            f32x4 cA0 = up4(nbA0), cA1 = up4(nbA1), cB0, cB1;
            if (hasB) { cB0 = up4(nbB0); cB1 = up4(nbB1); }
            if (kb < 384) {
                nbA0 = *(const bf16x4*)(BrA + kb + 32 + quad * 4);
                nbA1 = *(const bf16x4*)(BrA + kb + 48 + quad * 4);
                if (hasB) {
                    nbB0 = *(const bf16x4*)(BrB + kb + 32 + quad * 4);
                    nbB1 = *(const bf16x4*)(BrB + kb + 48 + quad * 4);
                }
            }
            f32x4 sA0 = MFMA(kf0, qfA, cA0);
            f32x4 sA1 = MFMA(kf1, qfA, cA1);
            bf16x4 pA0, pA1;
            float la = 0.f;
#pragma unroll
            for (int r = 0; r < 4; ++r) {
                float e0 = __builtin_amdgcn_exp2f(sA0[r]);
                float e1 = __builtin_amdgcn_exp2f(sA1[r]);
                pA0[r] = (bf16)e0; pA1[r] = (bf16)e1; la += e0 + e1;
            }
            lsA += la;
            *(bf16x4*)(PwA + l15 * 40 + quad * 4) = pA0;
            *(bf16x4*)(PwA + l15 * 40 + 16 + quad * 4) = pA1;
            if (hasB) {
                f32x4 sB0 = MFMA(kf0, qfB, cB0);
                f32x4 sB1 = MFMA(kf1, qfB, cB1);
                bf16x4 pB0, pB1;
                float lb = 0.f;
#pragma unroll
                for (int r = 0; r < 4; ++r) {
                    float e0 = __builtin_amdgcn_exp2f(sB0[r]);
                    float e1 = __builtin_amdgcn_exp2f(sB1[r]);
                    pB0[r] = (bf16)e0; pB1[r] = (bf16)e1; lb += e0 + e1;
                }
                lsB += lb;
                *(bf16x4*)(PwB + l15 * 40 + quad * 4) = pB0;
                *(bf16x4*)(PwB + l15 * 40 + 16 + quad * 4) = pB1;
            }
        };
        auto pv = [&](int kb) {
            bf16x8 pfA = *(const bf16x8*)(PwA + l15 * 40 + quad * 8);
            bf16x8 pfB;
            if (hasB) pfB = *(const bf16x8*)(PwB + l15 * 40 + quad * 8);
            bf16x8 vf0 = *(const bf16x8*)(&Vt[l15][kb + quad * 8]);
            bf16x8 vf1 = *(const bf16x8*)(&Vt[16 + l15][kb + quad * 8]);
            oA0 = MFMA(vf0, pfA, oA0);
            oA1 = MFMA(vf1, pfA, oA1);
            if (hasB) { oB0 = MFMA(vf0, pfB, oB0); oB1 = MFMA(vf1, pfB, oB1); }
        };

        qk_full(0);
#pragma unroll 1
        for (int kt = 1; kt < 12; ++kt) {
            pv((kt - 1) * 32);   // reads P(kt-1) BEFORE P(kt) writes: WAR-safe (DS in-order)
            qk_full(kt * 32);
        }
        pv(352);
        {   // kt = 12: only first 16-token half is (partially) real
            bf16x8 kf0 = *(const bf16x8*)(&Kl[384 + l15][quad * 8]);
            f32x4 cA0 = up4(nbA0), cB0;
            if (hasB) cB0 = up4(nbB0);
            f32x4 sA0 = MFMA(kf0, qfA, cA0);
            bf16x4 pA0, z4;
            float la = 0.f;
#pragma unroll
            for (int r = 0; r < 4; ++r) {
                float e0 = __builtin_amdgcn_exp2f(sA0[r]);
                pA0[r] = (bf16)e0; la += e0; z4[r] = (bf16)0.f;
            }
            lsA += la;
            *(bf16x4*)(PwA + l15 * 40 + quad * 4) = pA0;
            *(bf16x4*)(PwA + l15 * 40 + 16 + quad * 4) = z4;
            if (hasB) {
                f32x4 sB0 = MFMA(kf0, qfB, cB0);
                bf16x4 pB0;
                float lb = 0.f;
#pragma unroll
                for (int r = 0; r < 4; ++r) {
                    float e0 = __builtin_amdgcn_exp2f(sB0[r]);
                    pB0[r] = (bf16)e0; lb += e0;
                }
                lsB += lb;
                *(bf16x4*)(PwB + l15 * 40 + quad * 4) = pB0;
                *(bf16x4*)(PwB + l15 * 40 + 16 + quad * 4) = z4;
            }
        }
        pv(384);

        lsA += __shfl_xor(lsA, 16); lsA += __shfl_xor(lsA, 32);
        if (hasB) { lsB += __shfl_xor(lsB, 16); lsB += __shfl_xor(lsB, 32); }
        if (qbA + l15 < VOL) {
            float inv = 1.f / lsA;
            bf16x4 w0, w1;
#pragma unroll
            for (int r = 0; r < 4; ++r) { w0[r] = (bf16)(oA0[r] * inv); w1[r] = (bf16)(oA1[r] * inv); }
            bf16* dst = aows + ((size_t)win * VOL + qbA + l15) * Cc + head * HDc;
            *(bf16x4*)(dst + quad * 4) = w0;
            *(bf16x4*)(dst + 16 + quad * 4) = w1;
        }
        if (hasB && qbB + l15 < VOL) {
            float inv = 1.f / lsB;
            bf16x4 w0, w1;
#pragma unroll
            for (int r = 0; r < 4; ++r) { w0[r] = (bf16)(oB0[r] * inv); w1[r] = (bf16)(oB1[r] * inv); }
            bf16* dst = aows + ((size_t)win * VOL + qbB + l15) * Cc + head * HDc;
            *(bf16x4*)(dst + quad * 4) = w0;
            *(bf16x4*)(dst + 16 + quad * 4) = w1;
        }
    }
}

// ---------------------------------------------------------------------------
// Kernel 3: output projection + un-partition + roll-back scatter, fp32 out.
// DIRECT f32x4 global stores from MFMA fragments (full 64B segments per token
// row per mt -> no partial-sector amplification). LDS = As only.
// ---------------------------------------------------------------------------
__global__ __launch_bounds__(256, 4)
void proj_kernel(const bf16* __restrict__ aows, const bf16* __restrict__ wp,
                 const bf16* __restrict__ bp, float* __restrict__ out) {
    __shared__ bf16 As[64][136];
    __shared__ unsigned int rbo[64];
    const int tid = threadIdx.x;
    const int m0 = blockIdx.x * 64;

    if (tid < 64) {
        int g = m0 + tid;
        int win = g / VOL, tok = g % VOL;
        int b = win >> 7, wi = win & 127;
        int wt_i = wi >> 6, wh_i = (wi >> 3) & 7, ww_i = wi & 7;
        int tt = tok / 49, r2 = tok % 49, hh = r2 / 7, ww2 = r2 % 7;
        int t = wt_i * 8 + tt + STc; if (t >= Tc) t -= Tc;
        int h = wh_i * 7 + hh + SHc; if (h >= Hc) h -= Hc;
        int w = ww_i * 7 + ww2 + SWc; if (w >= Wc) w -= Wc;
        rbo[tid] = (unsigned int)((((b * Tc + t) * Hc + h) * Wc + w) * Cc * 4);
    }
    for (int idx = tid; idx < 64 * 16; idx += 256) {
        int r = idx >> 4, c = idx & 15;
        *(bf16x8*)(&As[r][c * 8]) = *(const bf16x8*)(aows + (size_t)(m0 + r) * Cc + c * 8);
    }
    __syncthreads();

    const int wid = tid >> 6, lane = tid & 63;
    const int quad = lane >> 4, l15 = lane & 15;

    f32x4 acc[8];  // mt over 128 output cols; rows = wid*16..+15
#pragma unroll
    for (int mt = 0; mt < 8; ++mt) acc[mt] = zf4();

#pragma unroll
    for (int ko = 0; ko < 4; ++ko) {
        bf16x8 xf = *(const bf16x8*)(&As[wid * 16 + l15][ko * 32 + quad * 8]);
#pragma unroll
        for (int mt = 0; mt < 8; ++mt) {
            bf16x8 wf = *(const bf16x8*)(wp + (size_t)(mt * 16 + l15) * Cc + ko * 32 + quad * 8);
            acc[mt] = MFMA(wf, xf, acc[mt]);  // C^T: m=col, n=row
        }
    }

    // Direct-store epilogue: lane holds row (wid*16+l15), cols colbase..+3 (f32x4).
    {
        char* rowp = (char*)out + rbo[wid * 16 + l15];
#pragma unroll
        for (int mt = 0; mt < 8; ++mt) {
            int colbase = mt * 16 + quad * 4;
            bf16x4 bc = *(const bf16x4*)(bp + colbase);
            f32x4 o;
#pragma unroll
            for (int r = 0; r < 4; ++r) o[r] = acc[mt][r] + (float)bc[r];
            *(f32x4*)((float*)rowp + colbase) = o;
        }
    }
}

extern "C" void kernel_launch(void* const* d_in, const int* in_sizes, int n_in,
                              void* d_out, int out_size, void* d_ws, size_t ws_size,
                              hipStream_t stream) {
    const float* x    = (const float*)d_in[0];
    const float* wqf  = (const float*)d_in[1];
    const float* bqf  = (const float*)d_in[2];
    const float* wpf  = (const float*)d_in[3];
    const float* bpf  = (const float*)d_in[4];
    const float* rpbf = (const float*)d_in[5];
    float* out = (float*)d_out;

    bf16* wqb  = (bf16*)d_ws;              // 49152
    bf16* bqb  = wqb + 49152;              // 384
    bf16* wpb  = bqb + 384;                // 16384
    bf16* bpb  = wpb + 16384;              // 128
    bf16* bmt  = bpb + 128;                // BMT_N = 5,324,800
    bf16* qws  = bmt + BMT_N;
    bf16* kws  = qws + QSZ;
    bf16* vws  = kws + QSZ;
    bf16* aows = vws + QSZ;

    hipLaunchKernelGGL(prep_kernel, dim3(865), dim3(256), 0, stream,
                       wqf, bqf, wpf, bpf, rpbf, wqb, bqb, wpb, bpb, bmt);
    hipLaunchKernelGGL(qkv_kernel, dim3(MTOT / 64), dim3(256), 0, stream,
                       x, wqb, bqb, qws, kws, vws);
    hipLaunchKernelGGL(attn_kernel, dim3(TWIN * NHc), dim3(512), 0, stream,
                       qws, kws, vws, bmt, aows);
    hipLaunchKernelGGL(proj_kernel, dim3(MTOT / 64), dim3(256), 0, stream,
                       aows, wpb, bpb, out);
}

// Round 4
// 264.757 us; speedup vs baseline: 1.1205x; 1.1205x over previous
//
#include <hip/hip_runtime.h>
#include <hip/hip_bf16.h>

typedef __bf16 bf16;
typedef __bf16 bf16x4 __attribute__((ext_vector_type(4)));
typedef __bf16 bf16x8 __attribute__((ext_vector_type(8)));
typedef float f32x4 __attribute__((ext_vector_type(4)));

#define MFMA(a, b, c) __builtin_amdgcn_mfma_f32_16x16x32_bf16(a, b, c, 0, 0, 0)

__device__ inline f32x4 zf4() { return f32x4{0.f, 0.f, 0.f, 0.f}; }

constexpr int Tc = 16, Hc = 56, Wc = 56, Cc = 128, NHc = 4, HDc = 32;
constexpr int VOL = 392;                 // 8*7*7 tokens per window
constexpr int STc = 4, SHc = 3, SWc = 3; // shift
constexpr int TWIN = 256;                // total windows (B * 128)
constexpr int MTOT = TWIN * VOL;         // 100352 tokens
constexpr int QSZ = TWIN * NHc * VOL * HDc;
constexpr int BMT_N = 8 * 4 * 400 * 416; // [pat][head][row][col] bias+mask table

__device__ inline bf16x8 zero8() {
    bf16x8 z;
#pragma unroll
    for (int j = 0; j < 8; ++j) z[j] = (bf16)0.0f;
    return z;
}

__device__ inline f32x4 up4(bf16x4 b) {
    f32x4 r;
#pragma unroll
    for (int j = 0; j < 4; ++j) r[j] = (float)b[j];
    return r;
}

__device__ inline int cls_of(int v, int pt, int ph, int pw) {
    int tt = v / 49, rem = v % 49, hh = rem / 7, ww = rem % 7;
    int ct = pt ? (tt < 4 ? 1 : 2) : 0;
    int ch = ph ? (hh < 4 ? 1 : 2) : 0;
    int cw = pw ? (ww < 4 ? 1 : 2) : 0;
    return ct * 9 + ch * 3 + cw;
}

// ---------------------------------------------------------------------------
// Kernel 0: fused prep. Blocks 0..64: fp32->bf16 param cvt.
// Blocks 65..864: bias+mask table bmt[pat8][head4][row400][col416] bf16 =
//   (rpb + mask)*log2e; pad col -> -144 (exp2 ~ 0), pad row -> 0.
// ---------------------------------------------------------------------------
__global__ void prep_kernel(const float* __restrict__ wq, const float* __restrict__ bq,
                            const float* __restrict__ wp, const float* __restrict__ bp,
                            const float* __restrict__ rpb,
                            bf16* __restrict__ wqb, bf16* __restrict__ bqb,
                            bf16* __restrict__ wpb, bf16* __restrict__ bpb,
                            bf16* __restrict__ bmt) {
    const int blk = blockIdx.x, tid = threadIdx.x;
    if (blk < 65) {
        int i = blk * 256 + tid;
        const float* s; bf16* d; int off;
        if (i < 12288)       { s = wq; d = wqb; off = i; }
        else if (i < 12384)  { s = bq; d = bqb; off = i - 12288; }
        else if (i < 16480)  { s = wp; d = wpb; off = i - 12384; }
        else if (i < 16512)  { s = bp; d = bpb; off = i - 16480; }
        else return;
        f32x4 v = *(const f32x4*)(s + (size_t)off * 4);
        bf16x4 o;
#pragma unroll
        for (int j = 0; j < 4; ++j) o[j] = (bf16)v[j];
        *(bf16x4*)(d + (size_t)off * 4) = o;
        return;
    }
    // bias blocks: bb = (pat, head, rowchunk of 16)
    __shared__ unsigned char clsc[392];
    int bb = blk - 65;
    int pat = bb / 100, rem = bb % 100;
    int head = rem / 25, rc = rem % 25;
    int pt = (pat >> 2) & 1, ph = (pat >> 1) & 1, pw = pat & 1;
    for (int v = tid; v < 392; v += 256) clsc[v] = (unsigned char)cls_of(v, pt, ph, pw);
    __syncthreads();
    bf16* dst = bmt + ((size_t)(pat * NHc + head) * 400 + rc * 16) * 416;
    for (int idx = tid; idx < 16 * 104; idx += 256) {
        int lr = idx / 104, c4 = idx % 104;
        int row = rc * 16 + lr;
        bf16x4 o;
        if (row >= VOL) {
#pragma unroll
            for (int j = 0; j < 4; ++j) o[j] = (bf16)0.f;
        } else {
            int rcls = clsc[row];
            const float* brow = rpb + (size_t)(head * VOL + row) * VOL;
#pragma unroll
            for (int j = 0; j < 4; ++j) {
                int col = c4 * 4 + j;
                float v;
                if (col >= VOL) v = -144.0f;
                else {
                    v = brow[col] * 1.4426950408889634f;
                    if (clsc[col] != rcls) v -= 144.0f;
                }
                o[j] = (bf16)v;
            }
        }
        *(bf16x4*)(dst + (size_t)lr * 416 + c4 * 4) = o;
    }
}

// ---------------------------------------------------------------------------
// Kernel 1: QKV projection (roll+partition fused gather, C^T-layout epilogue:
// lane holds 4 consecutive output cols -> b64 LDS writes).
// q pre-scaled by log2(e)/sqrt(32).
// NOTE: 2 blocks/CU + big-LDS staged epilogue is the measured-optimal config
// (70 us, 75 MB write). 4 blocks/CU variants explode fabric traffic 2.4x.
// ---------------------------------------------------------------------------
__global__ __launch_bounds__(256, 2)
void qkv_kernel(const float* __restrict__ x, const bf16* __restrict__ wq,
                const bf16* __restrict__ bq, bf16* __restrict__ qws,
                bf16* __restrict__ kws, bf16* __restrict__ vws) {
    __shared__ bf16 As[64][136];
    __shared__ bf16 Cs[64][396];
    __shared__ unsigned int rb[64];
    __shared__ unsigned int rbw[64];
    const int tid = threadIdx.x;
    const int m0 = blockIdx.x * 64;

    if (tid < 64) {
        int g = m0 + tid;
        int win = g / VOL, tok = g % VOL;
        int b = win >> 7, wi = win & 127;
        int wt_i = wi >> 6, wh_i = (wi >> 3) & 7, ww_i = wi & 7;
        int tt = tok / 49, r2 = tok % 49, hh = r2 / 7, ww2 = r2 % 7;
        int t = wt_i * 8 + tt + STc; if (t >= Tc) t -= Tc;
        int h = wh_i * 7 + hh + SHc; if (h >= Hc) h -= Hc;
        int w = ww_i * 7 + ww2 + SWc; if (w >= Wc) w -= Wc;
        rb[tid] = (unsigned int)((((b * Tc + t) * Hc + h) * Wc + w) * Cc * 4);
        rbw[tid] = (unsigned int)((win << 9) | tok);
    }
    __syncthreads();

    for (int idx = tid; idx < 64 * 32; idx += 256) {
        int r = idx >> 5, c = idx & 31;
        const float* src = (const float*)((const char*)x + rb[r]) + c * 4;
        f32x4 v = *(const f32x4*)src;
        bf16x4 o;
#pragma unroll
        for (int j = 0; j < 4; ++j) o[j] = (bf16)v[j];
        *(bf16x4*)(&As[r][c * 4]) = o;
    }
    __syncthreads();

    const int wid = tid >> 6, lane = tid & 63;
    const int quad = lane >> 4, l15 = lane & 15;
    const int nbase = wid * 96;

    f32x4 acc[6][4];  // [mt = W-col tile][nt = row tile]
#pragma unroll
    for (int mt = 0; mt < 6; ++mt)
#pragma unroll
        for (int nt = 0; nt < 4; ++nt) acc[mt][nt] = zf4();

#pragma unroll
    for (int ko = 0; ko < 4; ++ko) {
        bf16x8 xf[4];  // B-operand: x rows
#pragma unroll
        for (int nt = 0; nt < 4; ++nt)
            xf[nt] = *(const bf16x8*)(&As[nt * 16 + l15][ko * 32 + quad * 8]);
#pragma unroll
        for (int mt = 0; mt < 6; ++mt) {
            bf16x8 wf = *(const bf16x8*)(wq + (size_t)(nbase + mt * 16 + l15) * Cc + ko * 32 + quad * 8);
#pragma unroll
            for (int nt = 0; nt < 4; ++nt)
                acc[mt][nt] = MFMA(wf, xf[nt], acc[mt][nt]);  // C^T: m=col, n=row
        }
    }

#pragma unroll
    for (int mt = 0; mt < 6; ++mt) {
        int colbase = nbase + mt * 16 + quad * 4;
        bf16x4 bc = *(const bf16x4*)(bq + colbase);
        float scale = (colbase < 128) ? 0.25505653942f : 1.0f;  // log2e/sqrt(32) on q
#pragma unroll
        for (int nt = 0; nt < 4; ++nt) {
            bf16x4 o;
#pragma unroll
            for (int r = 0; r < 4; ++r)
                o[r] = (bf16)((acc[mt][nt][r] + (float)bc[r]) * scale);
            *(bf16x4*)(&Cs[nt * 16 + l15][colbase]) = o;
        }
    }
    __syncthreads();

    {
        int row = tid >> 2, hh4 = tid & 3;
        unsigned int p = rbw[row];
        int win = p >> 9, tok = p & 511;
        size_t off = ((size_t)(win * NHc + hh4) * VOL + tok) * HDc;
#pragma unroll
        for (int c = 0; c < 4; ++c) {
            bf16x4 lo = *(const bf16x4*)(&Cs[row][hh4 * 32 + c * 8]);
            bf16x4 hi = *(const bf16x4*)(&Cs[row][hh4 * 32 + c * 8 + 4]);
            *(bf16x8*)(qws + off + c * 8) = __builtin_shufflevector(lo, hi, 0, 1, 2, 3, 4, 5, 6, 7);
        }
#pragma unroll
        for (int c = 0; c < 4; ++c) {
            bf16x4 lo = *(const bf16x4*)(&Cs[row][128 + hh4 * 32 + c * 8]);
            bf16x4 hi = *(const bf16x4*)(&Cs[row][128 + hh4 * 32 + c * 8 + 4]);
            *(bf16x8*)(kws + off + c * 8) = __builtin_shufflevector(lo, hi, 0, 1, 2, 3, 4, 5, 6, 7);
        }
#pragma unroll
        for (int c = 0; c < 4; ++c) {
            bf16x4 lo = *(const bf16x4*)(&Cs[row][256 + hh4 * 32 + c * 8]);
            bf16x4 hi = *(const bf16x4*)(&Cs[row][256 + hh4 * 32 + c * 8 + 4]);
            *(bf16x8*)(vws + off + c * 8) = __builtin_shufflevector(lo, hi, 0, 1, 2, 3, 4, 5, 6, 7);
        }
    }
}

// ---------------------------------------------------------------------------
// Kernel 2: windowed attention, S^T formulation, pattern bias table, PV
// pipelined one kt behind QK. 512 thr/WG, one WG per (win,head), 2 q-tiles/wave.
// K and V LDS reads register-double-buffered (prefetch kt+1 fragments
// during kt's exp/MFMA phase) -> hides ~120cy LDS latency on the serial chain.
// ---------------------------------------------------------------------------
__global__ __launch_bounds__(512, 4)
void attn_kernel(const bf16* __restrict__ qws, const bf16* __restrict__ kws,
                 const bf16* __restrict__ vws, const bf16* __restrict__ bmt,
                 bf16* __restrict__ aows) {
    __shared__ bf16 Kl[400][40];      // rows 392..399 zero (kt12 is half-tile)
    __shared__ bf16 Vt[32][424];      // V transposed
    __shared__ bf16 Pb[8][2][16][40]; // per-wave, per-tile P

    const int tid = threadIdx.x;
    const int win = blockIdx.x >> 2, head = blockIdx.x & 3;
    const int wi = win & 127;
    const int wt_i = wi >> 6, wh_i = (wi >> 3) & 7, ww_i = wi & 7;
    const int pat = ((wt_i == 1) << 2) | ((wh_i == 7) << 1) | (ww_i == 7);

    const bf16* Qg = qws + (size_t)(win * NHc + head) * VOL * HDc;
    const bf16* Kg = kws + (size_t)(win * NHc + head) * VOL * HDc;
    const bf16* Vg = vws + (size_t)(win * NHc + head) * VOL * HDc;
    const bf16* Bg = bmt + (size_t)(pat * NHc + head) * 400 * 416;

    for (int idx = tid; idx < 400 * 4; idx += 512) {
        int tok = idx >> 2, c = idx & 3;
        bf16x8 v = zero8();
        if (tok < VOL) v = *(const bf16x8*)(Kg + tok * HDc + c * 8);
        *(bf16x8*)(&Kl[tok][c * 8]) = v;
    }
    if (tid < 416) {  // V transpose: b64 chunks of 4 toks
        int c = tid & 3, tok4 = (tid >> 2) * 4;
        bf16x8 rr[4];
#pragma unroll
        for (int i = 0; i < 4; ++i)
            rr[i] = (tok4 + i < VOL) ? *(const bf16x8*)(Vg + (tok4 + i) * HDc + c * 8) : zero8();
#pragma unroll
        for (int j = 0; j < 8; ++j) {
            bf16x4 wv;
            wv[0] = rr[0][j]; wv[1] = rr[1][j]; wv[2] = rr[2][j]; wv[3] = rr[3][j];
            *(bf16x4*)(&Vt[c * 8 + j][tok4]) = wv;
        }
    }
    __syncthreads();

    const int wid = tid >> 6, lane = tid & 63;
    const int quad = lane >> 4, l15 = lane & 15;
    bf16* PwA = &Pb[wid][0][0][0];
    bf16* PwB = &Pb[wid][1][0][0];

    for (int pass = 0; pass < 2; ++pass) {
        const int qtA = pass * 16 + wid, qtB = qtA + 8;
        const bool hasB = (qtB < 25);
        const int qbA = qtA * 16, qbB = qtB * 16;
        int qrA = qbA + l15; if (qrA >= VOL) qrA = VOL - 1;
        const bf16x8 qfA = *(const bf16x8*)(Qg + (size_t)qrA * HDc + quad * 8);
        const bf16* BrA = Bg + (size_t)(qbA + l15) * 416;
        const bf16* BrB = BrA;
        bf16x8 qfB;
        if (hasB) {
            int qrB = qbB + l15; if (qrB >= VOL) qrB = VOL - 1;
            qfB = *(const bf16x8*)(Qg + (size_t)qrB * HDc + quad * 8);
            BrB = Bg + (size_t)(qbB + l15) * 416;
        }
        f32x4 oA0 = zf4(), oA1 = zf4(), oB0 = zf4(), oB1 = zf4();
        float lsA = 0.f, lsB = 0.f;
        bf16x4 nbA0 = *(const bf16x4*)(BrA + quad * 4);
        bf16x4 nbA1 = *(const bf16x4*)(BrA + 16 + quad * 4);
        bf16x4 nbB0, nbB1;
        if (hasB) {
            nbB0 = *(const bf16x4*)(BrB + quad * 4);
            nbB1 = *(const bf16x4*)(BrB + 16 + quad * 4);
        }

        // register double-buffer: current K/V fragments (kc*, vc*), next (kn*, vn*)
        bf16x8 kc0 = *(const bf16x8*)(&Kl[l15][quad * 8]);
        bf16x8 kc1 = *(const bf16x8*)(&Kl[16 + l15][quad * 8]);
        bf16x8 vc0 = *(const bf16x8*)(&Vt[l15][quad * 8]);
        bf16x8 vc1 = *(const bf16x8*)(&Vt[16 + l15][quad * 8]);

        auto qk_full = [&](int kb) {
            bf16x8 kn0, kn1;
            if (kb < 384) {  // prefetch K(kt+1); kb=352 tail rows stay in-LDS (unused kc1)
                kn0 = *(const bf16x8*)(&Kl[kb + 32 + l15][quad * 8]);
                kn1 = *(const bf16x8*)(&Kl[kb + 48 + l15][quad * 8]);
            }
            f32x4 cA0 = up4(nbA0), cA1 = up4(nbA1), cB0, cB1;
            if (hasB) { cB0 = up4(nbB0); cB1 = up4(nbB1); }
            if (kb < 384) {
                nbA0 = *(const bf16x4*)(BrA + kb + 32 + quad * 4);
                nbA1 = *(const bf16x4*)(BrA + kb + 48 + quad * 4);
                if (hasB) {
                    nbB0 = *(const bf16x4*)(BrB + kb + 32 + quad * 4);
                    nbB1 = *(const bf16x4*)(BrB + kb + 48 + quad * 4);
                }
            }
            f32x4 sA0 = MFMA(kc0, qfA, cA0);
            f32x4 sA1 = MFMA(kc1, qfA, cA1);
            bf16x4 pA0, pA1;
            float la = 0.f;
#pragma unroll
            for (int r = 0; r < 4; ++r) {
                float e0 = __builtin_amdgcn_exp2f(sA0[r]);
                float e1 = __builtin_amdgcn_exp2f(sA1[r]);
                pA0[r] = (bf16)e0; pA1[r] = (bf16)e1; la += e0 + e1;
            }
            lsA += la;
            *(bf16x4*)(PwA + l15 * 40 + quad * 4) = pA0;
            *(bf16x4*)(PwA + l15 * 40 + 16 + quad * 4) = pA1;
            if (hasB) {
                f32x4 sB0 = MFMA(kc0, qfB, cB0);
                f32x4 sB1 = MFMA(kc1, qfB, cB1);
                bf16x4 pB0, pB1;
                float lb = 0.f;
#pragma unroll
                for (int r = 0; r < 4; ++r) {
                    float e0 = __builtin_amdgcn_exp2f(sB0[r]);
                    float e1 = __builtin_amdgcn_exp2f(sB1[r]);
                    pB0[r] = (bf16)e0; pB1[r] = (bf16)e1; lb += e0 + e1;
                }
                lsB += lb;
                *(bf16x4*)(PwB + l15 * 40 + quad * 4) = pB0;
                *(bf16x4*)(PwB + l15 * 40 + 16 + quad * 4) = pB1;
            }
            kc0 = kn0; kc1 = kn1;
        };
        auto pv = [&](int kb) {
            bf16x8 pfA = *(const bf16x8*)(PwA + l15 * 40 + quad * 8);
            bf16x8 pfB;
            if (hasB) pfB = *(const bf16x8*)(PwB + l15 * 40 + quad * 8);
            bf16x8 vn0, vn1;
            if (kb < 384) {  // prefetch V for next pv
                vn0 = *(const bf16x8*)(&Vt[l15][kb + 32 + quad * 8]);
                vn1 = *(const bf16x8*)(&Vt[16 + l15][kb + 32 + quad * 8]);
            }
            oA0 = MFMA(vc0, pfA, oA0);
            oA1 = MFMA(vc1, pfA, oA1);
            if (hasB) { oB0 = MFMA(vc0, pfB, oB0); oB1 = MFMA(vc1, pfB, oB1); }
            vc0 = vn0; vc1 = vn1;
        };

        qk_full(0);
#pragma unroll 1
        for (int kt = 1; kt < 12; ++kt) {
            pv((kt - 1) * 32);   // reads P(kt-1) BEFORE P(kt) writes: WAR-safe (DS in-order)
            qk_full(kt * 32);
        }
        pv(352);
        {   // kt = 12: only first 16-token half is (partially) real; kc0 = K[384..] (prefetched)
            f32x4 cA0 = up4(nbA0), cB0;
            if (hasB) cB0 = up4(nbB0);
            f32x4 sA0 = MFMA(kc0, qfA, cA0);
            bf16x4 pA0, z4;
            float la = 0.f;
#pragma unroll
            for (int r = 0; r < 4; ++r) {
                float e0 = __builtin_amdgcn_exp2f(sA0[r]);
                pA0[r] = (bf16)e0; la += e0; z4[r] = (bf16)0.f;
            }
            lsA += la;
            *(bf16x4*)(PwA + l15 * 40 + quad * 4) = pA0;
            *(bf16x4*)(PwA + l15 * 40 + 16 + quad * 4) = z4;
            if (hasB) {
                f32x4 sB0 = MFMA(kc0, qfB, cB0);
                bf16x4 pB0;
                float lb = 0.f;
#pragma unroll
                for (int r = 0; r < 4; ++r) {
                    float e0 = __builtin_amdgcn_exp2f(sB0[r]);
                    pB0[r] = (bf16)e0; lb += e0;
                }
                lsB += lb;
                *(bf16x4*)(PwB + l15 * 40 + quad * 4) = pB0;
                *(bf16x4*)(PwB + l15 * 40 + 16 + quad * 4) = z4;
            }
        }
        pv(384);

        lsA += __shfl_xor(lsA, 16); lsA += __shfl_xor(lsA, 32);
        if (hasB) { lsB += __shfl_xor(lsB, 16); lsB += __shfl_xor(lsB, 32); }
        if (qbA + l15 < VOL) {
            float inv = 1.f / lsA;
            bf16x4 w0, w1;
#pragma unroll
            for (int r = 0; r < 4; ++r) { w0[r] = (bf16)(oA0[r] * inv); w1[r] = (bf16)(oA1[r] * inv); }
            bf16* dst = aows + ((size_t)win * VOL + qbA + l15) * Cc + head * HDc;
            *(bf16x4*)(dst + quad * 4) = w0;
            *(bf16x4*)(dst + 16 + quad * 4) = w1;
        }
        if (hasB && qbB + l15 < VOL) {
            float inv = 1.f / lsB;
            bf16x4 w0, w1;
#pragma unroll
            for (int r = 0; r < 4; ++r) { w0[r] = (bf16)(oB0[r] * inv); w1[r] = (bf16)(oB1[r] * inv); }
            bf16* dst = aows + ((size_t)win * VOL + qbB + l15) * Cc + head * HDc;
            *(bf16x4*)(dst + quad * 4) = w0;
            *(bf16x4*)(dst + 16 + quad * 4) = w1;
        }
    }
}

// ---------------------------------------------------------------------------
// Kernel 3: output projection (C^T epilogue: f32x4 b128 LDS writes) +
// un-partition + roll-back scatter, fp32 out.
// ---------------------------------------------------------------------------
__global__ __launch_bounds__(256, 2)
void proj_kernel(const bf16* __restrict__ aows, const bf16* __restrict__ wp,
                 const bf16* __restrict__ bp, float* __restrict__ out) {
    __shared__ bf16 As[64][136];
    __shared__ float Csf[64][132];
    __shared__ unsigned int rbo[64];
    const int tid = threadIdx.x;
    const int m0 = blockIdx.x * 64;

    if (tid < 64) {
        int g = m0 + tid;
        int win = g / VOL, tok = g % VOL;
        int b = win >> 7, wi = win & 127;
        int wt_i = wi >> 6, wh_i = (wi >> 3) & 7, ww_i = wi & 7;
        int tt = tok / 49, r2 = tok % 49, hh = r2 / 7, ww2 = r2 % 7;
        int t = wt_i * 8 + tt + STc; if (t >= Tc) t -= Tc;
        int h = wh_i * 7 + hh + SHc; if (h >= Hc) h -= Hc;
        int w = ww_i * 7 + ww2 + SWc; if (w >= Wc) w -= Wc;
        rbo[tid] = (unsigned int)((((b * Tc + t) * Hc + h) * Wc + w) * Cc * 4);
    }
    for (int idx = tid; idx < 64 * 16; idx += 256) {
        int r = idx >> 4, c = idx & 15;
        *(bf16x8*)(&As[r][c * 8]) = *(const bf16x8*)(aows + (size_t)(m0 + r) * Cc + c * 8);
    }
    __syncthreads();

    const int wid = tid >> 6, lane = tid & 63;
    const int quad = lane >> 4, l15 = lane & 15;

    f32x4 acc[8];  // mt over 128 output cols; rows = wid*16..+15
#pragma unroll
    for (int mt = 0; mt < 8; ++mt) acc[mt] = zf4();

#pragma unroll
    for (int ko = 0; ko < 4; ++ko) {
        bf16x8 xf = *(const bf16x8*)(&As[wid * 16 + l15][ko * 32 + quad * 8]);
#pragma unroll
        for (int mt = 0; mt < 8; ++mt) {
            bf16x8 wf = *(const bf16x8*)(wp + (size_t)(mt * 16 + l15) * Cc + ko * 32 + quad * 8);
            acc[mt] = MFMA(wf, xf, acc[mt]);  // C^T: m=col, n=row
        }
    }
#pragma unroll
    for (int mt = 0; mt < 8; ++mt) {
        int colbase = mt * 16 + quad * 4;
        bf16x4 bc = *(const bf16x4*)(bp + colbase);
        f32x4 o;
#pragma unroll
        for (int r = 0; r < 4; ++r) o[r] = acc[mt][r] + (float)bc[r];
        *(f32x4*)(&Csf[wid * 16 + l15][colbase]) = o;
    }
    __syncthreads();

    for (int idx = tid; idx < 64 * 32; idx += 256) {
        int row = idx >> 5, ch = idx & 31;
        float* dst = (float*)((char*)out + rbo[row]) + ch * 4;
        *(f32x4*)dst = *(const f32x4*)(&Csf[row][ch * 4]);
    }
}

extern "C" void kernel_launch(void* const* d_in, const int* in_sizes, int n_in,
                              void* d_out, int out_size, void* d_ws, size_t ws_size,
                              hipStream_t stream) {
    const float* x    = (const float*)d_in[0];
    const float* wqf  = (const float*)d_in[1];
    const float* bqf  = (const float*)d_in[2];
    const float* wpf  = (const float*)d_in[3];
    const float* bpf  = (const float*)d_in[4];
    const float* rpbf = (const float*)d_in[5];
    float* out = (float*)d_out;

    bf16* wqb  = (bf16*)d_ws;              // 49152
    bf16* bqb  = wqb + 49152;              // 384
    bf16* wpb  = bqb + 384;                // 16384
    bf16* bpb  = wpb + 16384;              // 128
    bf16* bmt  = bpb + 128;                // BMT_N = 5,324,800
    bf16* qws  = bmt + BMT_N;
    bf16* kws  = qws + QSZ;
    bf16* vws  = kws + QSZ;
    bf16* aows = vws + QSZ;

    hipLaunchKernelGGL(prep_kernel, dim3(865), dim3(256), 0, stream,
                       wqf, bqf, wpf, bpf, rpbf, wqb, bqb, wpb, bpb, bmt);
    hipLaunchKernelGGL(qkv_kernel, dim3(MTOT / 64), dim3(256), 0, stream,
                       x, wqb, bqb, qws, kws, vws);
    hipLaunchKernelGGL(attn_kernel, dim3(TWIN * NHc), dim3(512), 0, stream,
                       qws, kws, vws, bmt, aows);
    hipLaunchKernelGGL(proj_kernel, dim3(MTOT / 64), dim3(256), 0, stream,
                       aows, wpb, bpb, out);
}

// Round 5
// 261.328 us; speedup vs baseline: 1.1352x; 1.0131x over previous
//
#include <hip/hip_runtime.h>
#include <hip/hip_bf16.h>

typedef __bf16 bf16;
typedef __bf16 bf16x4 __attribute__((ext_vector_type(4)));
typedef __bf16 bf16x8 __attribute__((ext_vector_type(8)));
typedef float f32x4 __attribute__((ext_vector_type(4)));

#define MFMA(a, b, c) __builtin_amdgcn_mfma_f32_16x16x32_bf16(a, b, c, 0, 0, 0)

__device__ inline f32x4 zf4() { return f32x4{0.f, 0.f, 0.f, 0.f}; }

constexpr int Tc = 16, Hc = 56, Wc = 56, Cc = 128, NHc = 4, HDc = 32;
constexpr int VOL = 392;                 // 8*7*7 tokens per window
constexpr int STc = 4, SHc = 3, SWc = 3; // shift
constexpr int TWIN = 256;                // total windows (B * 128)
constexpr int MTOT = TWIN * VOL;         // 100352 tokens
constexpr int QSZ = TWIN * NHc * VOL * HDc;
constexpr int BMT_N = 8 * 4 * 400 * 416; // [pat][head][row][col] bias+mask table

__device__ inline bf16x8 zero8() {
    bf16x8 z;
#pragma unroll
    for (int j = 0; j < 8; ++j) z[j] = (bf16)0.0f;
    return z;
}

__device__ inline f32x4 up4(bf16x4 b) {
    f32x4 r;
#pragma unroll
    for (int j = 0; j < 4; ++j) r[j] = (float)b[j];
    return r;
}

__device__ inline int cls_of(int v, int pt, int ph, int pw) {
    int tt = v / 49, rem = v % 49, hh = rem / 7, ww = rem % 7;
    int ct = pt ? (tt < 4 ? 1 : 2) : 0;
    int ch = ph ? (hh < 4 ? 1 : 2) : 0;
    int cw = pw ? (ww < 4 ? 1 : 2) : 0;
    return ct * 9 + ch * 3 + cw;
}

// ---------------------------------------------------------------------------
// Kernel 0: fused prep. Blocks 0..64: fp32->bf16 param cvt.
// Blocks 65..864: bias+mask table bmt[pat8][head4][row400][col416] bf16 =
//   (rpb + mask)*log2e; pad col -> -144 (exp2 ~ 0), pad row -> 0.
// ---------------------------------------------------------------------------
__global__ void prep_kernel(const float* __restrict__ wq, const float* __restrict__ bq,
                            const float* __restrict__ wp, const float* __restrict__ bp,
                            const float* __restrict__ rpb,
                            bf16* __restrict__ wqb, bf16* __restrict__ bqb,
                            bf16* __restrict__ wpb, bf16* __restrict__ bpb,
                            bf16* __restrict__ bmt) {
    const int blk = blockIdx.x, tid = threadIdx.x;
    if (blk < 65) {
        int i = blk * 256 + tid;
        const float* s; bf16* d; int off;
        if (i < 12288)       { s = wq; d = wqb; off = i; }
        else if (i < 12384)  { s = bq; d = bqb; off = i - 12288; }
        else if (i < 16480)  { s = wp; d = wpb; off = i - 12384; }
        else if (i < 16512)  { s = bp; d = bpb; off = i - 16480; }
        else return;
        f32x4 v = *(const f32x4*)(s + (size_t)off * 4);
        bf16x4 o;
#pragma unroll
        for (int j = 0; j < 4; ++j) o[j] = (bf16)v[j];
        *(bf16x4*)(d + (size_t)off * 4) = o;
        return;
    }
    // bias blocks: bb = (pat, head, rowchunk of 16)
    __shared__ unsigned char clsc[392];
    int bb = blk - 65;
    int pat = bb / 100, rem = bb % 100;
    int head = rem / 25, rc = rem % 25;
    int pt = (pat >> 2) & 1, ph = (pat >> 1) & 1, pw = pat & 1;
    for (int v = tid; v < 392; v += 256) clsc[v] = (unsigned char)cls_of(v, pt, ph, pw);
    __syncthreads();
    bf16* dst = bmt + ((size_t)(pat * NHc + head) * 400 + rc * 16) * 416;
    for (int idx = tid; idx < 16 * 104; idx += 256) {
        int lr = idx / 104, c4 = idx % 104;
        int row = rc * 16 + lr;
        bf16x4 o;
        if (row >= VOL) {
#pragma unroll
            for (int j = 0; j < 4; ++j) o[j] = (bf16)0.f;
        } else {
            int rcls = clsc[row];
            const float* brow = rpb + (size_t)(head * VOL + row) * VOL;
#pragma unroll
            for (int j = 0; j < 4; ++j) {
                int col = c4 * 4 + j;
                float v;
                if (col >= VOL) v = -144.0f;
                else {
                    v = brow[col] * 1.4426950408889634f;
                    if (clsc[col] != rcls) v -= 144.0f;
                }
                o[j] = (bf16)v;
            }
        }
        *(bf16x4*)(dst + (size_t)lr * 416 + c4 * 4) = o;
    }
}

// ---------------------------------------------------------------------------
// Kernel 1: QKV projection (roll+partition fused gather, C^T-layout epilogue).
// Epilogue split into two 192-col phases (waves 0-1: q + k.h01; waves 2-3:
// k.h23 + v) -> Cs shrinks 50.7->26.1 KB -> LDS 44 KB -> 3 blocks/CU.
// Global store pattern byte-identical to the proven 75MB-write epilogue.
// q pre-scaled by log2(e)/sqrt(32).
// ---------------------------------------------------------------------------
__global__ __launch_bounds__(256, 3)
void qkv_kernel(const float* __restrict__ x, const bf16* __restrict__ wq,
                const bf16* __restrict__ bq, bf16* __restrict__ qws,
                bf16* __restrict__ kws, bf16* __restrict__ vws) {
    __shared__ bf16 As[64][136];
    __shared__ bf16 Cs[64][204];   // 204: 8B-aligned rows (408B), 192 cols + pad
    __shared__ unsigned int rb[64];
    __shared__ unsigned int rbw[64];
    const int tid = threadIdx.x;
    const int m0 = blockIdx.x * 64;

    if (tid < 64) {
        int g = m0 + tid;
        int win = g / VOL, tok = g % VOL;
        int b = win >> 7, wi = win & 127;
        int wt_i = wi >> 6, wh_i = (wi >> 3) & 7, ww_i = wi & 7;
        int tt = tok / 49, r2 = tok % 49, hh = r2 / 7, ww2 = r2 % 7;
        int t = wt_i * 8 + tt + STc; if (t >= Tc) t -= Tc;
        int h = wh_i * 7 + hh + SHc; if (h >= Hc) h -= Hc;
        int w = ww_i * 7 + ww2 + SWc; if (w >= Wc) w -= Wc;
        rb[tid] = (unsigned int)((((b * Tc + t) * Hc + h) * Wc + w) * Cc * 4);
        rbw[tid] = (unsigned int)((win << 9) | tok);
    }
    __syncthreads();

    for (int idx = tid; idx < 64 * 32; idx += 256) {
        int r = idx >> 5, c = idx & 31;
        const float* src = (const float*)((const char*)x + rb[r]) + c * 4;
        f32x4 v = *(const f32x4*)src;
        bf16x4 o;
#pragma unroll
        for (int j = 0; j < 4; ++j) o[j] = (bf16)v[j];
        *(bf16x4*)(&As[r][c * 4]) = o;
    }
    __syncthreads();

    const int wid = tid >> 6, lane = tid & 63;
    const int quad = lane >> 4, l15 = lane & 15;
    const int nbase = wid * 96;

    f32x4 acc[6][4];  // [mt = W-col tile][nt = row tile]
#pragma unroll
    for (int mt = 0; mt < 6; ++mt)
#pragma unroll
        for (int nt = 0; nt < 4; ++nt) acc[mt][nt] = zf4();

#pragma unroll
    for (int ko = 0; ko < 4; ++ko) {
        bf16x8 xf[4];  // B-operand: x rows
#pragma unroll
        for (int nt = 0; nt < 4; ++nt)
            xf[nt] = *(const bf16x8*)(&As[nt * 16 + l15][ko * 32 + quad * 8]);
#pragma unroll
        for (int mt = 0; mt < 6; ++mt) {
            bf16x8 wf = *(const bf16x8*)(wq + (size_t)(nbase + mt * 16 + l15) * Cc + ko * 32 + quad * 8);
#pragma unroll
            for (int nt = 0; nt < 4; ++nt)
                acc[mt][nt] = MFMA(wf, xf[nt], acc[mt][nt]);  // C^T: m=col, n=row
        }
    }

    // Two-phase epilogue: phase 0 = cols [0,192) (waves 0,1), phase 1 = [192,384).
#pragma unroll 1
    for (int phase = 0; phase < 2; ++phase) {
        if ((wid >> 1) == phase) {
#pragma unroll
            for (int mt = 0; mt < 6; ++mt) {
                int colbase = nbase + mt * 16 + quad * 4;
                int lc = colbase - phase * 192;   // in [0,192)
                bf16x4 bc = *(const bf16x4*)(bq + colbase);
                float scale = (colbase < 128) ? 0.25505653942f : 1.0f;  // log2e/sqrt(32) on q
#pragma unroll
                for (int nt = 0; nt < 4; ++nt) {
                    bf16x4 o;
#pragma unroll
                    for (int r = 0; r < 4; ++r)
                        o[r] = (bf16)((acc[mt][nt][r] + (float)bc[r]) * scale);
                    *(bf16x4*)(&Cs[nt * 16 + l15][lc]) = o;
                }
            }
        }
        __syncthreads();
        // store 64 rows x 6 head-slices of 32 cols each (same global pattern as r0)
        for (int u = tid; u < 64 * 6; u += 256) {
            int row = u / 6, s = u - row * 6;
            int gs = phase * 6 + s;   // 0..3 q.h, 4..7 k.h, 8..11 v.h
            bf16* basep = (gs < 4) ? qws : (gs < 8) ? kws : vws;
            int head = gs & 3;
            unsigned int p = rbw[row];
            int win = p >> 9, tok = p & 511;
            size_t off = ((size_t)(win * NHc + head) * VOL + tok) * HDc;
#pragma unroll
            for (int c = 0; c < 4; ++c) {
                bf16x4 lo = *(const bf16x4*)(&Cs[row][s * 32 + c * 8]);
                bf16x4 hi = *(const bf16x4*)(&Cs[row][s * 32 + c * 8 + 4]);
                *(bf16x8*)(basep + off + c * 8) = __builtin_shufflevector(lo, hi, 0, 1, 2, 3, 4, 5, 6, 7);
            }
        }
        __syncthreads();
    }
}

// ---------------------------------------------------------------------------
// Kernel 2: windowed attention, S^T formulation, pattern bias table, PV
// pipelined one kt behind QK. 512 thr/WG, one WG per (win,head), 2 q-tiles/wave.
// K and V LDS reads register-double-buffered (prefetch kt+1 fragments
// during kt's exp/MFMA phase) -> hides ~120cy LDS latency on the serial chain.
// ---------------------------------------------------------------------------
__global__ __launch_bounds__(512, 4)
void attn_kernel(const bf16* __restrict__ qws, const bf16* __restrict__ kws,
                 const bf16* __restrict__ vws, const bf16* __restrict__ bmt,
                 bf16* __restrict__ aows) {
    __shared__ bf16 Kl[400][40];      // rows 392..399 zero (kt12 is half-tile)
    __shared__ bf16 Vt[32][424];      // V transposed
    __shared__ bf16 Pb[8][2][16][40]; // per-wave, per-tile P

    const int tid = threadIdx.x;
    const int win = blockIdx.x >> 2, head = blockIdx.x & 3;
    const int wi = win & 127;
    const int wt_i = wi >> 6, wh_i = (wi >> 3) & 7, ww_i = wi & 7;
    const int pat = ((wt_i == 1) << 2) | ((wh_i == 7) << 1) | (ww_i == 7);

    const bf16* Qg = qws + (size_t)(win * NHc + head) * VOL * HDc;
    const bf16* Kg = kws + (size_t)(win * NHc + head) * VOL * HDc;
    const bf16* Vg = vws + (size_t)(win * NHc + head) * VOL * HDc;
    const bf16* Bg = bmt + (size_t)(pat * NHc + head) * 400 * 416;

    for (int idx = tid; idx < 400 * 4; idx += 512) {
        int tok = idx >> 2, c = idx & 3;
        bf16x8 v = zero8();
        if (tok < VOL) v = *(const bf16x8*)(Kg + tok * HDc + c * 8);
        *(bf16x8*)(&Kl[tok][c * 8]) = v;
    }
    if (tid < 416) {  // V transpose: b64 chunks of 4 toks
        int c = tid & 3, tok4 = (tid >> 2) * 4;
        bf16x8 rr[4];
#pragma unroll
        for (int i = 0; i < 4; ++i)
            rr[i] = (tok4 + i < VOL) ? *(const bf16x8*)(Vg + (tok4 + i) * HDc + c * 8) : zero8();
#pragma unroll
        for (int j = 0; j < 8; ++j) {
            bf16x4 wv;
            wv[0] = rr[0][j]; wv[1] = rr[1][j]; wv[2] = rr[2][j]; wv[3] = rr[3][j];
            *(bf16x4*)(&Vt[c * 8 + j][tok4]) = wv;
        }
    }
    __syncthreads();

    const int wid = tid >> 6, lane = tid & 63;
    const int quad = lane >> 4, l15 = lane & 15;
    bf16* PwA = &Pb[wid][0][0][0];
    bf16* PwB = &Pb[wid][1][0][0];

    for (int pass = 0; pass < 2; ++pass) {
        const int qtA = pass * 16 + wid, qtB = qtA + 8;
        const bool hasB = (qtB < 25);
        const int qbA = qtA * 16, qbB = qtB * 16;
        int qrA = qbA + l15; if (qrA >= VOL) qrA = VOL - 1;
        const bf16x8 qfA = *(const bf16x8*)(Qg + (size_t)qrA * HDc + quad * 8);
        const bf16* BrA = Bg + (size_t)(qbA + l15) * 416;
        const bf16* BrB = BrA;
        bf16x8 qfB;
        if (hasB) {
            int qrB = qbB + l15; if (qrB >= VOL) qrB = VOL - 1;
            qfB = *(const bf16x8*)(Qg + (size_t)qrB * HDc + quad * 8);
            BrB = Bg + (size_t)(qbB + l15) * 416;
        }
        f32x4 oA0 = zf4(), oA1 = zf4(), oB0 = zf4(), oB1 = zf4();
        float lsA = 0.f, lsB = 0.f;
        bf16x4 nbA0 = *(const bf16x4*)(BrA + quad * 4);
        bf16x4 nbA1 = *(const bf16x4*)(BrA + 16 + quad * 4);
        bf16x4 nbB0, nbB1;
        if (hasB) {
            nbB0 = *(const bf16x4*)(BrB + quad * 4);
            nbB1 = *(const bf16x4*)(BrB + 16 + quad * 4);
        }

        // register double-buffer: current K/V fragments (kc*, vc*), next (kn*, vn*)
        bf16x8 kc0 = *(const bf16x8*)(&Kl[l15][quad * 8]);
        bf16x8 kc1 = *(const bf16x8*)(&Kl[16 + l15][quad * 8]);
        bf16x8 vc0 = *(const bf16x8*)(&Vt[l15][quad * 8]);
        bf16x8 vc1 = *(const bf16x8*)(&Vt[16 + l15][quad * 8]);

        auto qk_full = [&](int kb) {
            bf16x8 kn0, kn1;
            if (kb < 384) {  // prefetch K(kt+1); kb=352 tail rows stay in-LDS (unused kc1)
                kn0 = *(const bf16x8*)(&Kl[kb + 32 + l15][quad * 8]);
                kn1 = *(const bf16x8*)(&Kl[kb + 48 + l15][quad * 8]);
            }
            f32x4 cA0 = up4(nbA0), cA1 = up4(nbA1), cB0, cB1;
            if (hasB) { cB0 = up4(nbB0); cB1 = up4(nbB1); }
            if (kb < 384) {
                nbA0 = *(const bf16x4*)(BrA + kb + 32 + quad * 4);
                nbA1 = *(const bf16x4*)(BrA + kb + 48 + quad * 4);
                if (hasB) {
                    nbB0 = *(const bf16x4*)(BrB + kb + 32 + quad * 4);
                    nbB1 = *(const bf16x4*)(BrB + kb + 48 + quad * 4);
                }
            }
            f32x4 sA0 = MFMA(kc0, qfA, cA0);
            f32x4 sA1 = MFMA(kc1, qfA, cA1);
            bf16x4 pA0, pA1;
            float la = 0.f;
#pragma unroll
            for (int r = 0; r < 4; ++r) {
                float e0 = __builtin_amdgcn_exp2f(sA0[r]);
                float e1 = __builtin_amdgcn_exp2f(sA1[r]);
                pA0[r] = (bf16)e0; pA1[r] = (bf16)e1; la += e0 + e1;
            }
            lsA += la;
            *(bf16x4*)(PwA + l15 * 40 + quad * 4) = pA0;
            *(bf16x4*)(PwA + l15 * 40 + 16 + quad * 4) = pA1;
            if (hasB) {
                f32x4 sB0 = MFMA(kc0, qfB, cB0);
                f32x4 sB1 = MFMA(kc1, qfB, cB1);
                bf16x4 pB0, pB1;
                float lb = 0.f;
#pragma unroll
                for (int r = 0; r < 4; ++r) {
                    float e0 = __builtin_amdgcn_exp2f(sB0[r]);
                    float e1 = __builtin_amdgcn_exp2f(sB1[r]);
                    pB0[r] = (bf16)e0; pB1[r] = (bf16)e1; lb += e0 + e1;
                }
                lsB += lb;
                *(bf16x4*)(PwB + l15 * 40 + quad * 4) = pB0;
                *(bf16x4*)(PwB + l15 * 40 + 16 + quad * 4) = pB1;
            }
            kc0 = kn0; kc1 = kn1;
        };
        auto pv = [&](int kb) {
            bf16x8 pfA = *(const bf16x8*)(PwA + l15 * 40 + quad * 8);
            bf16x8 pfB;
            if (hasB) pfB = *(const bf16x8*)(PwB + l15 * 40 + quad * 8);
            bf16x8 vn0, vn1;
            if (kb < 384) {  // prefetch V for next pv
                vn0 = *(const bf16x8*)(&Vt[l15][kb + 32 + quad * 8]);
                vn1 = *(const bf16x8*)(&Vt[16 + l15][kb + 32 + quad * 8]);
            }
            oA0 = MFMA(vc0, pfA, oA0);
            oA1 = MFMA(vc1, pfA, oA1);
            if (hasB) { oB0 = MFMA(vc0, pfB, oB0); oB1 = MFMA(vc1, pfB, oB1); }
            vc0 = vn0; vc1 = vn1;
        };

        qk_full(0);
#pragma unroll 1
        for (int kt = 1; kt < 12; ++kt) {
            pv((kt - 1) * 32);   // reads P(kt-1) BEFORE P(kt) writes: WAR-safe (DS in-order)
            qk_full(kt * 32);
        }
        pv(352);
        {   // kt = 12: only first 16-token half is (partially) real; kc0 = K[384..] (prefetched)
            f32x4 cA0 = up4(nbA0), cB0;
            if (hasB) cB0 = up4(nbB0);
            f32x4 sA0 = MFMA(kc0, qfA, cA0);
            bf16x4 pA0, z4;
            float la = 0.f;
#pragma unroll
            for (int r = 0; r < 4; ++r) {
                float e0 = __builtin_amdgcn_exp2f(sA0[r]);
                pA0[r] = (bf16)e0; la += e0; z4[r] = (bf16)0.f;
            }
            lsA += la;
            *(bf16x4*)(PwA + l15 * 40 + quad * 4) = pA0;
            *(bf16x4*)(PwA + l15 * 40 + 16 + quad * 4) = z4;
            if (hasB) {
                f32x4 sB0 = MFMA(kc0, qfB, cB0);
                bf16x4 pB0;
                float lb = 0.f;
#pragma unroll
                for (int r = 0; r < 4; ++r) {
                    float e0 = __builtin_amdgcn_exp2f(sB0[r]);
                    pB0[r] = (bf16)e0; lb += e0;
                }
                lsB += lb;
                *(bf16x4*)(PwB + l15 * 40 + quad * 4) = pB0;
                *(bf16x4*)(PwB + l15 * 40 + 16 + quad * 4) = z4;
            }
        }
        pv(384);

        lsA += __shfl_xor(lsA, 16); lsA += __shfl_xor(lsA, 32);
        if (hasB) { lsB += __shfl_xor(lsB, 16); lsB += __shfl_xor(lsB, 32); }
        if (qbA + l15 < VOL) {
            float inv = 1.f / lsA;
            bf16x4 w0, w1;
#pragma unroll
            for (int r = 0; r < 4; ++r) { w0[r] = (bf16)(oA0[r] * inv); w1[r] = (bf16)(oA1[r] * inv); }
            bf16* dst = aows + ((size_t)win * VOL + qbA + l15) * Cc + head * HDc;
            *(bf16x4*)(dst + quad * 4) = w0;
            *(bf16x4*)(dst + 16 + quad * 4) = w1;
        }
        if (hasB && qbB + l15 < VOL) {
            float inv = 1.f / lsB;
            bf16x4 w0, w1;
#pragma unroll
            for (int r = 0; r < 4; ++r) { w0[r] = (bf16)(oB0[r] * inv); w1[r] = (bf16)(oB1[r] * inv); }
            bf16* dst = aows + ((size_t)win * VOL + qbB + l15) * Cc + head * HDc;
            *(bf16x4*)(dst + quad * 4) = w0;
            *(bf16x4*)(dst + 16 + quad * 4) = w1;
        }
    }
}

// ---------------------------------------------------------------------------
// Kernel 3: output projection (C^T epilogue: f32x4 b128 LDS writes) +
// un-partition + roll-back scatter, fp32 out.
// ---------------------------------------------------------------------------
__global__ __launch_bounds__(256, 2)
void proj_kernel(const bf16* __restrict__ aows, const bf16* __restrict__ wp,
                 const bf16* __restrict__ bp, float* __restrict__ out) {
    __shared__ bf16 As[64][136];
    __shared__ float Csf[64][132];
    __shared__ unsigned int rbo[64];
    const int tid = threadIdx.x;
    const int m0 = blockIdx.x * 64;

    if (tid < 64) {
        int g = m0 + tid;
        int win = g / VOL, tok = g % VOL;
        int b = win >> 7, wi = win & 127;
        int wt_i = wi >> 6, wh_i = (wi >> 3) & 7, ww_i = wi & 7;
        int tt = tok / 49, r2 = tok % 49, hh = r2 / 7, ww2 = r2 % 7;
        int t = wt_i * 8 + tt + STc; if (t >= Tc) t -= Tc;
        int h = wh_i * 7 + hh + SHc; if (h >= Hc) h -= Hc;
        int w = ww_i * 7 + ww2 + SWc; if (w >= Wc) w -= Wc;
        rbo[tid] = (unsigned int)((((b * Tc + t) * Hc + h) * Wc + w) * Cc * 4);
    }
    for (int idx = tid; idx < 64 * 16; idx += 256) {
        int r = idx >> 4, c = idx & 15;
        *(bf16x8*)(&As[r][c * 8]) = *(const bf16x8*)(aows + (size_t)(m0 + r) * Cc + c * 8);
    }
    __syncthreads();

    const int wid = tid >> 6, lane = tid & 63;
    const int quad = lane >> 4, l15 = lane & 15;

    f32x4 acc[8];  // mt over 128 output cols; rows = wid*16..+15
#pragma unroll
    for (int mt = 0; mt < 8; ++mt) acc[mt] = zf4();

#pragma unroll
    for (int ko = 0; ko < 4; ++ko) {
        bf16x8 xf = *(const bf16x8*)(&As[wid * 16 + l15][ko * 32 + quad * 8]);
#pragma unroll
        for (int mt = 0; mt < 8; ++mt) {
            bf16x8 wf = *(const bf16x8*)(wp + (size_t)(mt * 16 + l15) * Cc + ko * 32 + quad * 8);
            acc[mt] = MFMA(wf, xf, acc[mt]);  // C^T: m=col, n=row
        }
    }
#pragma unroll
    for (int mt = 0; mt < 8; ++mt) {
        int colbase = mt * 16 + quad * 4;
        bf16x4 bc = *(const bf16x4*)(bp + colbase);
        f32x4 o;
#pragma unroll
        for (int r = 0; r < 4; ++r) o[r] = acc[mt][r] + (float)bc[r];
        *(f32x4*)(&Csf[wid * 16 + l15][colbase]) = o;
    }
    __syncthreads();

    for (int idx = tid; idx < 64 * 32; idx += 256) {
        int row = idx >> 5, ch = idx & 31;
        float* dst = (float*)((char*)out + rbo[row]) + ch * 4;
        *(f32x4*)dst = *(const f32x4*)(&Csf[row][ch * 4]);
    }
}

extern "C" void kernel_launch(void* const* d_in, const int* in_sizes, int n_in,
                              void* d_out, int out_size, void* d_ws, size_t ws_size,
                              hipStream_t stream) {
    const float* x    = (const float*)d_in[0];
    const float* wqf  = (const float*)d_in[1];
    const float* bqf  = (const float*)d_in[2];
    const float* wpf  = (const float*)d_in[3];
    const float* bpf  = (const float*)d_in[4];
    const float* rpbf = (const float*)d_in[5];
    float* out = (float*)d_out;

    bf16* wqb  = (bf16*)d_ws;              // 49152
    bf16* bqb  = wqb + 49152;              // 384
    bf16* wpb  = bqb + 384;                // 16384
    bf16* bpb  = wpb + 16384;              // 128
    bf16* bmt  = bpb + 128;                // BMT_N = 5,324,800
    bf16* qws  = bmt + BMT_N;
    bf16* kws  = qws + QSZ;
    bf16* vws  = kws + QSZ;
    bf16* aows = vws + QSZ;

    hipLaunchKernelGGL(prep_kernel, dim3(865), dim3(256), 0, stream,
                       wqf, bqf, wpf, bpf, rpbf, wqb, bqb, wpb, bpb, bmt);
    hipLaunchKernelGGL(qkv_kernel, dim3(MTOT / 64), dim3(256), 0, stream,
                       x, wqb, bqb, qws, kws, vws);
    hipLaunchKernelGGL(attn_kernel, dim3(TWIN * NHc), dim3(512), 0, stream,
                       qws, kws, vws, bmt, aows);
    hipLaunchKernelGGL(proj_kernel, dim3(MTOT / 64), dim3(256), 0, stream,
                       aows, wpb, bpb, out);
}